// Round 6
// baseline (210.067 us; speedup 1.0000x reference)
//
#include <hip/hip_runtime.h>
#include <hip/hip_bf16.h>

#define SEQ_LEN   20
#define USER_LEN  256
#define NTOK      (SEQ_LEN * USER_LEN)   // 5120
#define NC        64
#define CAND_N    1024
#define HID       128
#define TOPK      10
#define RHO_C     0.02f

#define CAND_BLKS 256                    // 65536 threads, 1/candidate
#define TO_BLKS   (NTOK / 256)           // 20
#define SEQ_BLKS  (NTOK / 256)           // 20
#define MAXB      (NTOK / 8 + NC)        // 704 max (centroid,8-token) groups

// ---------------------------------------------------------------------------
// Kernel A: four roles, thread-per-item MLPs with CHUNKED hidden accumulation
// (hc[8] live instead of h[40] -> no scratch spill; inputs re-streamed per
// chunk, L1-resident). Weight indices are wave-uniform -> scalar loads.
//   [0,256)    : candidate-table MLP -> tab[c][d][j], tab[c][20][j]=|v|^2
//   [256,276)  : per-token "to" MLP  -> aX[n][20]
//   [276,296)  : per-token "seq" MLP -> aH[n][20]
//   296        : bucketing (hist -> scan -> scatter -> block map)
// ---------------------------------------------------------------------------
__global__ __launch_bounds__(256) void k_pre(
    const int* __restrict__ x, const int* __restrict__ t_slot,
    const float* __restrict__ vecs, const float* __restrict__ temb,
    const int* __restrict__ I_array, const int* __restrict__ cand,
    const float* __restrict__ Ws1, const float* __restrict__ bs1,
    const float* __restrict__ Ws2, const float* __restrict__ bs2,
    const float* __restrict__ Wt1, const float* __restrict__ bt1,
    const float* __restrict__ Wt2, const float* __restrict__ bt2,
    const float* __restrict__ Wc1, const float* __restrict__ bc1,
    const float* __restrict__ Wc2, const float* __restrict__ bc2,
    float* __restrict__ tab, float* __restrict__ aX, float* __restrict__ aH,
    int* __restrict__ bucket, int* __restrict__ blkInfo) {
  int tid = threadIdx.x;

  if (blockIdx.x < CAND_BLKS) {
    // ---------------- candidate-table role: 1 thread / candidate ----------
    int g = blockIdx.x * 256 + tid;            // (c,j) slot
    int v = cand[g];
    const float4* vp = (const float4*)(vecs + (size_t)v * 20);
    const float4* tp = (const float4*)(temb + 40);       // time_embeddings[2]

    float o[20];
    #pragma unroll
    for (int k = 0; k < 20; k++) o[k] = bc2[k];

    #pragma unroll 1
    for (int cc = 0; cc < 5; cc++) {           // hidden chunk: units cc*8..+7
      float hc[8];
      #pragma unroll
      for (int jj = 0; jj < 8; jj++) hc[jj] = bc1[cc * 8 + jj];
      // time part (uniform across lanes)
      #pragma unroll
      for (int q = 0; q < 5; q++) {
        float4 e = tp[q];
        #pragma unroll
        for (int r = 0; r < 4; r++) {
          float xi = (&e.x)[r];
          #pragma unroll
          for (int jj = 0; jj < 8; jj++)
            hc[jj] = fmaf(xi, Wc1[(20 + 4 * q + r) * 40 + cc * 8 + jj], hc[jj]);
        }
      }
      // location part
      #pragma unroll
      for (int q = 0; q < 5; q++) {
        float4 e = vp[q];
        #pragma unroll
        for (int r = 0; r < 4; r++) {
          float xi = (&e.x)[r];
          #pragma unroll
          for (int jj = 0; jj < 8; jj++)
            hc[jj] = fmaf(xi, Wc1[(4 * q + r) * 40 + cc * 8 + jj], hc[jj]);
        }
      }
      // layer 2 accumulation (i = cc*8+jj ascending across chunks)
      #pragma unroll
      for (int jj = 0; jj < 8; jj++) {
        float hv = fmaxf(hc[jj], 0.f);
        #pragma unroll
        for (int k = 0; k < 20; k++)
          o[k] = fmaf(hv, Wc2[(cc * 8 + jj) * 20 + k], o[k]);
      }
    }
    int c = g >> 10, j = g & 1023;
    float* op = tab + (size_t)c * (21 * CAND_N) + j;
    float nrm = 0.f;
    #pragma unroll
    for (int k = 0; k < 20; k++) {
      op[k * CAND_N] = o[k];
      nrm = fmaf(o[k], o[k], nrm);
    }
    op[20 * CAND_N] = nrm;

  } else if (blockIdx.x < CAND_BLKS + TO_BLKS) {
    // ---------------- "to" MLP role: 1 thread / token ----------------------
    int n = (blockIdx.x - CAND_BLKS) * 256 + tid;
    int xv = x[n];
    int ts = t_slot[n];
    int h24 = ts % 24;
    int seg = (h24 >= 22 || h24 < 6) ? 0 : (h24 < 14 ? 1 : 2);
    const float4* ep = (const float4*)(vecs + (size_t)xv * 20);
    const float4* tp = (const float4*)(temb + seg * 20);   // 80B-aligned

    float o[20];
    #pragma unroll
    for (int k = 0; k < 20; k++) o[k] = bt2[k];

    #pragma unroll 1
    for (int cc = 0; cc < 5; cc++) {
      float hc[8];
      #pragma unroll
      for (int jj = 0; jj < 8; jj++) hc[jj] = bt1[cc * 8 + jj];
      #pragma unroll
      for (int q = 0; q < 5; q++) {
        float4 e = ep[q];
        #pragma unroll
        for (int r = 0; r < 4; r++) {
          float xi = (&e.x)[r];
          #pragma unroll
          for (int jj = 0; jj < 8; jj++)
            hc[jj] = fmaf(xi, Wt1[(4 * q + r) * 40 + cc * 8 + jj], hc[jj]);
        }
      }
      #pragma unroll
      for (int q = 0; q < 5; q++) {
        float4 e = tp[q];
        #pragma unroll
        for (int r = 0; r < 4; r++) {
          float xi = (&e.x)[r];
          #pragma unroll
          for (int jj = 0; jj < 8; jj++)
            hc[jj] = fmaf(xi, Wt1[(20 + 4 * q + r) * 40 + cc * 8 + jj], hc[jj]);
        }
      }
      #pragma unroll
      for (int jj = 0; jj < 8; jj++) {
        float hv = fmaxf(hc[jj], 0.f);
        #pragma unroll
        for (int k = 0; k < 20; k++)
          o[k] = fmaf(hv, Wt2[(cc * 8 + jj) * 20 + k], o[k]);
      }
    }
    #pragma unroll
    for (int k = 0; k < 20; k++) aX[n * 20 + k] = o[k];

  } else if (blockIdx.x < CAND_BLKS + TO_BLKS + SEQ_BLKS) {
    // ---------------- "seq" MLP role: 1 thread / token ---------------------
    int n = (blockIdx.x - CAND_BLKS - TO_BLKS) * 256 + tid;
    int s = n >> 8, u = n & 255;
    int xv2[5];
    #pragma unroll
    for (int b = 0; b < 5; b++) {
      int sh = 4 - b;                        // b=4 -> sh=0 -> current token
      int row = (s >= sh) ? s - sh : s;
      xv2[b] = x[row * USER_LEN + u];
    }

    float o[20];
    #pragma unroll
    for (int k = 0; k < 20; k++) o[k] = bs2[k];

    #pragma unroll 1
    for (int cc = 0; cc < 5; cc++) {
      float hc[8];
      #pragma unroll
      for (int jj = 0; jj < 8; jj++) hc[jj] = bs1[cc * 8 + jj];
      #pragma unroll 1
      for (int b = 0; b < 5; b++) {
        const float4* p = (const float4*)(vecs + (size_t)xv2[b] * 20);
        #pragma unroll
        for (int q = 0; q < 5; q++) {
          float4 e = p[q];
          #pragma unroll
          for (int r = 0; r < 4; r++) {
            float xi = (&e.x)[r];
            #pragma unroll
            for (int jj = 0; jj < 8; jj++)
              hc[jj] = fmaf(xi, Ws1[(b * 20 + 4 * q + r) * 40 + cc * 8 + jj], hc[jj]);
          }
        }
      }
      #pragma unroll
      for (int jj = 0; jj < 8; jj++) {
        float hv = fmaxf(hc[jj], 0.f);
        #pragma unroll
        for (int k = 0; k < 20; k++)
          o[k] = fmaf(hv, Ws2[(cc * 8 + jj) * 20 + k], o[k]);
      }
    }
    #pragma unroll
    for (int k = 0; k < 20; k++) aH[n * 20 + k] = o[k];

  } else {
    // ---------------- bucketing role (single block) ------------------------
    __shared__ int lc[NC];
    __shared__ int lcur[NC];
    if (tid < NC) lc[tid] = 0;
    for (int b = tid; b < MAXB; b += 256) blkInfo[b] = -1;
    __syncthreads();
    for (int n = tid; n < NTOK; n += 256)
      atomicAdd(&lc[I_array[x[n]]], 1);
    __syncthreads();

    int v = 0, myStart = 0, nb = 0, blkStart = 0;
    if (tid < 64) {
      v = lc[tid];
      int inc = v;
      #pragma unroll
      for (int d = 1; d < 64; d <<= 1) {
        int t2 = __shfl_up(inc, d);
        if (tid >= d) inc += t2;
      }
      myStart = inc - v;
      lcur[tid] = myStart;
      nb = (v + 7) >> 3;
      int nbs = nb;
      #pragma unroll
      for (int d = 1; d < 64; d <<= 1) {
        int t2 = __shfl_up(nbs, d);
        if (tid >= d) nbs += t2;
      }
      blkStart = nbs - nb;
    }
    __syncthreads();
    for (int n = tid; n < NTOK; n += 256) {
      int c = I_array[x[n]];
      int p = atomicAdd(&lcur[c], 1);
      bucket[p] = n;
    }
    if (tid < 64) {
      for (int k = 0; k < nb; k++) {
        int rem = v - 8 * k;
        int tc = rem < 8 ? rem : 8;
        blkInfo[blkStart + k] = (tid << 20) | (tc << 16) | (myStart + 8 * k);
      }
    }
  }
}

// ---------------------------------------------------------------------------
// Kernel B: fused distance + selection + output. One block per <=8 tokens of
// one centroid. a = 0.5*(aH+aX) and |a|^2 computed during staging.
// ---------------------------------------------------------------------------
__global__ __launch_bounds__(256) void k_distsel(
    const int* __restrict__ blkInfo, const int* __restrict__ bucket,
    const float* __restrict__ tab, const float* __restrict__ aX,
    const float* __restrict__ aH, const int* __restrict__ x,
    const int* __restrict__ cand, const float* __restrict__ emb,
    float* __restrict__ out) {
  int info = blkInfo[blockIdx.x];
  if (info < 0) return;
  int start = info & 0xFFFF;
  int tcnt  = (info >> 16) & 0xF;      // 1..8
  int c     = info >> 20;

  __shared__ float sA[8][20];
  __shared__ float sN[8];
  __shared__ int   sTok[8];
  __shared__ float sD[8][CAND_N];      // 32 KB

  int tid = threadIdx.x;
  if (tid < 8) sTok[tid] = (tid < tcnt) ? bucket[start + tid] : -1;
  if (tid < 160) {
    int tt = tid / 20, d = tid - tt * 20;
    if (tt < tcnt) {
      int n = bucket[start + tt];
      sA[tt][d] = 0.5f * (aH[n * 20 + d] + aX[n * 20 + d]);
    } else {
      sA[tt][d] = 0.f;
    }
  }
  __syncthreads();
  if (tid < 8) {
    float nrm = 0.f;
    #pragma unroll
    for (int d = 0; d < 20; d++) nrm = fmaf(sA[tid][d], sA[tid][d], nrm);
    sN[tid] = nrm;
  }
  __syncthreads();

  // ---- distance tile: 8x20 @ 20x1024 ----
  const float* T = tab + (size_t)c * (21 * CAND_N);
  int j4 = tid * 4;
  float4 acc[8];
  #pragma unroll
  for (int tt = 0; tt < 8; tt++) acc[tt] = make_float4(0.f, 0.f, 0.f, 0.f);
  #pragma unroll
  for (int dq = 0; dq < 5; dq++) {
    float4 t0 = *(const float4*)(T + (dq * 4 + 0) * CAND_N + j4);
    float4 t1 = *(const float4*)(T + (dq * 4 + 1) * CAND_N + j4);
    float4 t2 = *(const float4*)(T + (dq * 4 + 2) * CAND_N + j4);
    float4 t3 = *(const float4*)(T + (dq * 4 + 3) * CAND_N + j4);
    #pragma unroll
    for (int tt = 0; tt < 8; tt++) {
      float4 av = *(const float4*)(&sA[tt][dq * 4]);   // LDS broadcast
      acc[tt].x = fmaf(av.x, t0.x, acc[tt].x);
      acc[tt].y = fmaf(av.x, t0.y, acc[tt].y);
      acc[tt].z = fmaf(av.x, t0.z, acc[tt].z);
      acc[tt].w = fmaf(av.x, t0.w, acc[tt].w);
      acc[tt].x = fmaf(av.y, t1.x, acc[tt].x);
      acc[tt].y = fmaf(av.y, t1.y, acc[tt].y);
      acc[tt].z = fmaf(av.y, t1.z, acc[tt].z);
      acc[tt].w = fmaf(av.y, t1.w, acc[tt].w);
      acc[tt].x = fmaf(av.z, t2.x, acc[tt].x);
      acc[tt].y = fmaf(av.z, t2.y, acc[tt].y);
      acc[tt].z = fmaf(av.z, t2.z, acc[tt].z);
      acc[tt].w = fmaf(av.z, t2.w, acc[tt].w);
      acc[tt].x = fmaf(av.w, t3.x, acc[tt].x);
      acc[tt].y = fmaf(av.w, t3.y, acc[tt].y);
      acc[tt].z = fmaf(av.w, t3.z, acc[tt].z);
      acc[tt].w = fmaf(av.w, t3.w, acc[tt].w);
    }
  }
  float4 cn4 = *(const float4*)(T + 20 * CAND_N + j4);
  #pragma unroll
  for (int tt = 0; tt < 8; tt++) {
    float4 d2;
    d2.x = sN[tt] + cn4.x - 2.f * acc[tt].x;
    d2.y = sN[tt] + cn4.y - 2.f * acc[tt].y;
    d2.z = sN[tt] + cn4.z - 2.f * acc[tt].z;
    d2.w = sN[tt] + cn4.w - 2.f * acc[tt].w;
    *(float4*)(&sD[tt][j4]) = d2;
  }
  __syncthreads();

  // ---- selection: wave w handles tokens w and w+4 ----
  int lane = tid & 63, w = tid >> 6;
  #pragma unroll 1
  for (int pass = 0; pass < 2; pass++) {
    int tt = w + 4 * pass;
    if (tt >= tcnt) continue;
    int n = sTok[tt];
    int xv = x[n];

    float v[16];
    #pragma unroll
    for (int m = 0; m < 16; m++) v[m] = sD[tt][m * 64 + lane];  // j = m*64+lane

    float acc0 = 0.f, acc1 = 0.f, esum = 0.f;
    #pragma unroll 1
    for (int r = 0; r < TOPK; r++) {
      float bv = v[0];
      int bj = lane;
      #pragma unroll
      for (int m = 1; m < 16; m++) {
        int jm = (m << 6) | lane;
        if (v[m] < bv) { bv = v[m]; bj = jm; }     // m asc => j asc, < keeps low j
      }
      #pragma unroll
      for (int o = 1; o < 64; o <<= 1) {
        float ov = __shfl_xor(bv, o);
        int   oj = __shfl_xor(bj, o);
        if (ov < bv || (ov == bv && oj < bj)) { bv = ov; bj = oj; }
      }
      float dist = sqrtf(fmaxf(bv, 1e-12f));
      float e = expf(expf(-RHO_C * dist));
      int id = cand[c * CAND_N + bj];
      esum += e;
      acc0 = fmaf(e, emb[(size_t)id * HID + lane], acc0);
      acc1 = fmaf(e, emb[(size_t)id * HID + 64 + lane], acc1);
      #pragma unroll
      for (int m = 0; m < 16; m++) {
        int jm = (m << 6) | lane;
        if (jm == bj) v[m] = 3.0e38f;
      }
    }
    const float e1 = 2.71828182845904523536f;      // exp(1.0) self slot
    esum += e1;
    acc0 = fmaf(e1, emb[(size_t)xv * HID + lane], acc0);
    acc1 = fmaf(e1, emb[(size_t)xv * HID + 64 + lane], acc1);
    float inv = 1.0f / esum;
    out[(size_t)n * HID + lane] = acc0 * inv;
    out[(size_t)n * HID + 64 + lane] = acc1 * inv;
  }
}

// ---------------------------------------------------------------------------
extern "C" void kernel_launch(void* const* d_in, const int* in_sizes, int n_in,
                              void* d_out, int out_size, void* d_ws, size_t ws_size,
                              hipStream_t stream) {
  const int*   x      = (const int*)d_in[0];
  const int*   t_slot = (const int*)d_in[1];
  const float* vecs   = (const float*)d_in[2];
  const float* embn   = (const float*)d_in[3];
  const int*   I_arr  = (const int*)d_in[4];
  const int*   cand   = (const int*)d_in[5];
  const float* temb   = (const float*)d_in[6];
  const float* Ws1    = (const float*)d_in[7];
  const float* bs1    = (const float*)d_in[8];
  const float* Ws2    = (const float*)d_in[9];
  const float* bs2    = (const float*)d_in[10];
  const float* Wto1   = (const float*)d_in[11];
  const float* bto1   = (const float*)d_in[12];
  const float* Wto2   = (const float*)d_in[13];
  const float* bto2   = (const float*)d_in[14];
  const float* Wti1   = (const float*)d_in[15];
  const float* bti1   = (const float*)d_in[16];
  const float* Wti2   = (const float*)d_in[17];
  const float* bti2   = (const float*)d_in[18];

  // workspace layout (~6.3 MB)
  float* tab    = (float*)d_ws;                       // 64*21*1024
  float* aX     = tab + NC * 21 * CAND_N;             // 5120*20
  float* aH     = aX + NTOK * 20;                     // 5120*20
  int*   bucket = (int*)(aH + NTOK * 20);             // 5120
  int*   blkInfo= bucket + NTOK;                      // 704
  float* outp   = (float*)d_out;

  k_pre<<<CAND_BLKS + TO_BLKS + SEQ_BLKS + 1, 256, 0, stream>>>(
      x, t_slot, vecs, temb, I_arr, cand,
      Ws1, bs1, Ws2, bs2, Wto1, bto1, Wto2, bto2,
      Wti1, bti1, Wti2, bti2,
      tab, aX, aH, bucket, blkInfo);
  k_distsel<<<MAXB, 256, 0, stream>>>(blkInfo, bucket, tab, aX, aH,
                                      x, cand, embn, outp);
}

// Round 7
// 177.480 us; speedup vs baseline: 1.1836x; 1.1836x over previous
//
#include <hip/hip_runtime.h>
#include <hip/hip_bf16.h>

#define SEQ_LEN   20
#define USER_LEN  256
#define NTOK      (SEQ_LEN * USER_LEN)   // 5120
#define NC        64
#define CAND_N    1024
#define HID       128
#define TOPK      10
#define RHO_C     0.02f

#define CAND_BLKS 256                    // 65536 threads, 1/candidate
#define TO_BLKS   (NTOK / 256)           // 20
#define SEQ_BLKS  (NTOK / 256)           // 20
#define MAXB      (NTOK / 8 + NC)        // 704 max (centroid,8-token) groups

// ---------------------------------------------------------------------------
// Kernel A: four roles. MLP weights staged in LDS (lane-uniform ds_read_b128
// broadcasts replace the s_load stall chains that made R6 latency-bound).
// Chunked hc[8] accumulation (no spills). Math order identical to R5/R6.
//   [0,256)    : candidate-table MLP -> tab[c][d][j], tab[c][20][j]=|v|^2
//   [256,276)  : per-token "to" MLP  -> aX[n][20]
//   [276,296)  : per-token "seq" MLP -> aH[n][20]
//   296        : bucketing (hist -> scan -> scatter -> block map)
// ---------------------------------------------------------------------------
__global__ __launch_bounds__(256) void k_pre(
    const int* __restrict__ x, const int* __restrict__ t_slot,
    const float* __restrict__ vecs, const float* __restrict__ temb,
    const int* __restrict__ I_array, const int* __restrict__ cand,
    const float* __restrict__ Ws1, const float* __restrict__ bs1,
    const float* __restrict__ Ws2, const float* __restrict__ bs2,
    const float* __restrict__ Wt1, const float* __restrict__ bt1,
    const float* __restrict__ Wt2, const float* __restrict__ bt2,
    const float* __restrict__ Wc1, const float* __restrict__ bc1,
    const float* __restrict__ Wc2, const float* __restrict__ bc2,
    float* __restrict__ tab, float* __restrict__ aX, float* __restrict__ aH,
    int* __restrict__ bucket, int* __restrict__ blkInfo) {
  __shared__ float sWS[4800];            // 19.2 KB, role-dependent layout
  int tid = threadIdx.x;

  if (blockIdx.x < CAND_BLKS) {
    // ---------------- candidate-table role: 1 thread / candidate ----------
    {
      float4* dst = (float4*)sWS;
      const float4* s1 = (const float4*)Wc1;       // 400 float4
      for (int i = tid; i < 400; i += 256) dst[i] = s1[i];
      const float4* s2 = (const float4*)Wc2;       // 200 float4
      for (int i = tid; i < 200; i += 256) dst[400 + i] = s2[i];
    }
    __syncthreads();
    const float* sW1 = sWS;             // [40][40]
    const float* sW2 = sWS + 1600;      // [40][20]

    int g = blockIdx.x * 256 + tid;            // (c,j) slot
    int v = cand[g];
    const float4* vp = (const float4*)(vecs + (size_t)v * 20);
    const float4* tp = (const float4*)(temb + 40);       // time_embeddings[2]

    float o[20];
    #pragma unroll
    for (int k = 0; k < 20; k++) o[k] = bc2[k];

    #pragma unroll 1
    for (int cc = 0; cc < 5; cc++) {           // hidden chunk: units cc*8..+7
      float hc[8];
      #pragma unroll
      for (int jj = 0; jj < 8; jj++) hc[jj] = bc1[cc * 8 + jj];
      // time part (i = 20..39)
      #pragma unroll
      for (int q = 0; q < 5; q++) {
        float4 e = tp[q];
        #pragma unroll
        for (int r = 0; r < 4; r++) {
          float xi = (&e.x)[r];
          const float* wr = &sW1[(20 + 4 * q + r) * 40 + cc * 8];
          float4 w0 = *(const float4*)(wr);
          float4 w1 = *(const float4*)(wr + 4);
          hc[0] = fmaf(xi, w0.x, hc[0]); hc[1] = fmaf(xi, w0.y, hc[1]);
          hc[2] = fmaf(xi, w0.z, hc[2]); hc[3] = fmaf(xi, w0.w, hc[3]);
          hc[4] = fmaf(xi, w1.x, hc[4]); hc[5] = fmaf(xi, w1.y, hc[5]);
          hc[6] = fmaf(xi, w1.z, hc[6]); hc[7] = fmaf(xi, w1.w, hc[7]);
        }
      }
      // location part (i = 0..19)
      #pragma unroll
      for (int q = 0; q < 5; q++) {
        float4 e = vp[q];
        #pragma unroll
        for (int r = 0; r < 4; r++) {
          float xi = (&e.x)[r];
          const float* wr = &sW1[(4 * q + r) * 40 + cc * 8];
          float4 w0 = *(const float4*)(wr);
          float4 w1 = *(const float4*)(wr + 4);
          hc[0] = fmaf(xi, w0.x, hc[0]); hc[1] = fmaf(xi, w0.y, hc[1]);
          hc[2] = fmaf(xi, w0.z, hc[2]); hc[3] = fmaf(xi, w0.w, hc[3]);
          hc[4] = fmaf(xi, w1.x, hc[4]); hc[5] = fmaf(xi, w1.y, hc[5]);
          hc[6] = fmaf(xi, w1.z, hc[6]); hc[7] = fmaf(xi, w1.w, hc[7]);
        }
      }
      // layer 2 (i ascending across chunks)
      #pragma unroll
      for (int jj = 0; jj < 8; jj++) {
        float hv = fmaxf(hc[jj], 0.f);
        const float* wr = &sW2[(cc * 8 + jj) * 20];
        #pragma unroll
        for (int kq = 0; kq < 5; kq++) {
          float4 w = *(const float4*)(wr + 4 * kq);
          o[kq * 4 + 0] = fmaf(hv, w.x, o[kq * 4 + 0]);
          o[kq * 4 + 1] = fmaf(hv, w.y, o[kq * 4 + 1]);
          o[kq * 4 + 2] = fmaf(hv, w.z, o[kq * 4 + 2]);
          o[kq * 4 + 3] = fmaf(hv, w.w, o[kq * 4 + 3]);
        }
      }
    }
    int c = g >> 10, j = g & 1023;
    float* op = tab + (size_t)c * (21 * CAND_N) + j;
    float nrm = 0.f;
    #pragma unroll
    for (int k = 0; k < 20; k++) {
      op[k * CAND_N] = o[k];
      nrm = fmaf(o[k], o[k], nrm);
    }
    op[20 * CAND_N] = nrm;

  } else if (blockIdx.x < CAND_BLKS + TO_BLKS) {
    // ---------------- "to" MLP role: 1 thread / token ----------------------
    {
      float4* dst = (float4*)sWS;
      const float4* s1 = (const float4*)Wt1;       // 400 float4
      for (int i = tid; i < 400; i += 256) dst[i] = s1[i];
      const float4* s2 = (const float4*)Wt2;       // 200 float4
      for (int i = tid; i < 200; i += 256) dst[400 + i] = s2[i];
    }
    __syncthreads();
    const float* sW1 = sWS;
    const float* sW2 = sWS + 1600;

    int n = (blockIdx.x - CAND_BLKS) * 256 + tid;
    int xv = x[n];
    int ts = t_slot[n];
    int h24 = ts % 24;
    int seg = (h24 >= 22 || h24 < 6) ? 0 : (h24 < 14 ? 1 : 2);
    const float4* ep = (const float4*)(vecs + (size_t)xv * 20);
    const float4* tp = (const float4*)(temb + seg * 20);   // 80B-aligned

    float o[20];
    #pragma unroll
    for (int k = 0; k < 20; k++) o[k] = bt2[k];

    #pragma unroll 1
    for (int cc = 0; cc < 5; cc++) {
      float hc[8];
      #pragma unroll
      for (int jj = 0; jj < 8; jj++) hc[jj] = bt1[cc * 8 + jj];
      #pragma unroll
      for (int q = 0; q < 5; q++) {              // location i = 0..19
        float4 e = ep[q];
        #pragma unroll
        for (int r = 0; r < 4; r++) {
          float xi = (&e.x)[r];
          const float* wr = &sW1[(4 * q + r) * 40 + cc * 8];
          float4 w0 = *(const float4*)(wr);
          float4 w1 = *(const float4*)(wr + 4);
          hc[0] = fmaf(xi, w0.x, hc[0]); hc[1] = fmaf(xi, w0.y, hc[1]);
          hc[2] = fmaf(xi, w0.z, hc[2]); hc[3] = fmaf(xi, w0.w, hc[3]);
          hc[4] = fmaf(xi, w1.x, hc[4]); hc[5] = fmaf(xi, w1.y, hc[5]);
          hc[6] = fmaf(xi, w1.z, hc[6]); hc[7] = fmaf(xi, w1.w, hc[7]);
        }
      }
      #pragma unroll
      for (int q = 0; q < 5; q++) {              // time i = 20..39
        float4 e = tp[q];
        #pragma unroll
        for (int r = 0; r < 4; r++) {
          float xi = (&e.x)[r];
          const float* wr = &sW1[(20 + 4 * q + r) * 40 + cc * 8];
          float4 w0 = *(const float4*)(wr);
          float4 w1 = *(const float4*)(wr + 4);
          hc[0] = fmaf(xi, w0.x, hc[0]); hc[1] = fmaf(xi, w0.y, hc[1]);
          hc[2] = fmaf(xi, w0.z, hc[2]); hc[3] = fmaf(xi, w0.w, hc[3]);
          hc[4] = fmaf(xi, w1.x, hc[4]); hc[5] = fmaf(xi, w1.y, hc[5]);
          hc[6] = fmaf(xi, w1.z, hc[6]); hc[7] = fmaf(xi, w1.w, hc[7]);
        }
      }
      #pragma unroll
      for (int jj = 0; jj < 8; jj++) {
        float hv = fmaxf(hc[jj], 0.f);
        const float* wr = &sW2[(cc * 8 + jj) * 20];
        #pragma unroll
        for (int kq = 0; kq < 5; kq++) {
          float4 w = *(const float4*)(wr + 4 * kq);
          o[kq * 4 + 0] = fmaf(hv, w.x, o[kq * 4 + 0]);
          o[kq * 4 + 1] = fmaf(hv, w.y, o[kq * 4 + 1]);
          o[kq * 4 + 2] = fmaf(hv, w.z, o[kq * 4 + 2]);
          o[kq * 4 + 3] = fmaf(hv, w.w, o[kq * 4 + 3]);
        }
      }
    }
    #pragma unroll
    for (int k = 0; k < 20; k++) aX[n * 20 + k] = o[k];

  } else if (blockIdx.x < CAND_BLKS + TO_BLKS + SEQ_BLKS) {
    // ---------------- "seq" MLP role: 1 thread / token ---------------------
    {
      float4* dst = (float4*)sWS;
      const float4* s1 = (const float4*)Ws1;       // 1000 float4
      for (int i = tid; i < 1000; i += 256) dst[i] = s1[i];
      const float4* s2 = (const float4*)Ws2;       // 200 float4
      for (int i = tid; i < 200; i += 256) dst[1000 + i] = s2[i];
    }
    __syncthreads();
    const float* sW1 = sWS;             // [100][40]
    const float* sW2 = sWS + 4000;      // [40][20]

    int n = (blockIdx.x - CAND_BLKS - TO_BLKS) * 256 + tid;
    int s = n >> 8, u = n & 255;
    int xv2[5];
    #pragma unroll
    for (int b = 0; b < 5; b++) {
      int sh = 4 - b;                        // b=4 -> sh=0 -> current token
      int row = (s >= sh) ? s - sh : s;
      xv2[b] = x[row * USER_LEN + u];
    }

    float o[20];
    #pragma unroll
    for (int k = 0; k < 20; k++) o[k] = bs2[k];

    #pragma unroll 1
    for (int cc = 0; cc < 5; cc++) {
      float hc[8];
      #pragma unroll
      for (int jj = 0; jj < 8; jj++) hc[jj] = bs1[cc * 8 + jj];
      #pragma unroll 1
      for (int b = 0; b < 5; b++) {
        const float4* p = (const float4*)(vecs + (size_t)xv2[b] * 20);
        #pragma unroll
        for (int q = 0; q < 5; q++) {
          float4 e = p[q];
          #pragma unroll
          for (int r = 0; r < 4; r++) {
            float xi = (&e.x)[r];
            const float* wr = &sW1[(b * 20 + 4 * q + r) * 40 + cc * 8];
            float4 w0 = *(const float4*)(wr);
            float4 w1 = *(const float4*)(wr + 4);
            hc[0] = fmaf(xi, w0.x, hc[0]); hc[1] = fmaf(xi, w0.y, hc[1]);
            hc[2] = fmaf(xi, w0.z, hc[2]); hc[3] = fmaf(xi, w0.w, hc[3]);
            hc[4] = fmaf(xi, w1.x, hc[4]); hc[5] = fmaf(xi, w1.y, hc[5]);
            hc[6] = fmaf(xi, w1.z, hc[6]); hc[7] = fmaf(xi, w1.w, hc[7]);
          }
        }
      }
      #pragma unroll
      for (int jj = 0; jj < 8; jj++) {
        float hv = fmaxf(hc[jj], 0.f);
        const float* wr = &sW2[(cc * 8 + jj) * 20];
        #pragma unroll
        for (int kq = 0; kq < 5; kq++) {
          float4 w = *(const float4*)(wr + 4 * kq);
          o[kq * 4 + 0] = fmaf(hv, w.x, o[kq * 4 + 0]);
          o[kq * 4 + 1] = fmaf(hv, w.y, o[kq * 4 + 1]);
          o[kq * 4 + 2] = fmaf(hv, w.z, o[kq * 4 + 2]);
          o[kq * 4 + 3] = fmaf(hv, w.w, o[kq * 4 + 3]);
        }
      }
    }
    #pragma unroll
    for (int k = 0; k < 20; k++) aH[n * 20 + k] = o[k];

  } else {
    // ---------------- bucketing role (single block) ------------------------
    int* lc = (int*)sWS;
    int* lcur = lc + NC;
    if (tid < NC) lc[tid] = 0;
    for (int b = tid; b < MAXB; b += 256) blkInfo[b] = -1;
    __syncthreads();
    for (int n = tid; n < NTOK; n += 256)
      atomicAdd(&lc[I_array[x[n]]], 1);
    __syncthreads();

    int v = 0, myStart = 0, nb = 0, blkStart = 0;
    if (tid < 64) {
      v = lc[tid];
      int inc = v;
      #pragma unroll
      for (int d = 1; d < 64; d <<= 1) {
        int t2 = __shfl_up(inc, d);
        if (tid >= d) inc += t2;
      }
      myStart = inc - v;
      lcur[tid] = myStart;
      nb = (v + 7) >> 3;
      int nbs = nb;
      #pragma unroll
      for (int d = 1; d < 64; d <<= 1) {
        int t2 = __shfl_up(nbs, d);
        if (tid >= d) nbs += t2;
      }
      blkStart = nbs - nb;
    }
    __syncthreads();
    for (int n = tid; n < NTOK; n += 256) {
      int c = I_array[x[n]];
      int p = atomicAdd(&lcur[c], 1);
      bucket[p] = n;
    }
    if (tid < 64) {
      for (int k = 0; k < nb; k++) {
        int rem = v - 8 * k;
        int tc = rem < 8 ? rem : 8;
        blkInfo[blkStart + k] = (tid << 20) | (tc << 16) | (myStart + 8 * k);
      }
    }
  }
}

// ---------------------------------------------------------------------------
// Kernel B: fused distance + selection + output. One block per <=8 tokens of
// one centroid. a = 0.5*(aH+aX) and |a|^2 computed during staging.
// ---------------------------------------------------------------------------
__global__ __launch_bounds__(256) void k_distsel(
    const int* __restrict__ blkInfo, const int* __restrict__ bucket,
    const float* __restrict__ tab, const float* __restrict__ aX,
    const float* __restrict__ aH, const int* __restrict__ x,
    const int* __restrict__ cand, const float* __restrict__ emb,
    float* __restrict__ out) {
  int info = blkInfo[blockIdx.x];
  if (info < 0) return;
  int start = info & 0xFFFF;
  int tcnt  = (info >> 16) & 0xF;      // 1..8
  int c     = info >> 20;

  __shared__ float sA[8][20];
  __shared__ float sN[8];
  __shared__ int   sTok[8];
  __shared__ float sD[8][CAND_N];      // 32 KB

  int tid = threadIdx.x;
  if (tid < 8) sTok[tid] = (tid < tcnt) ? bucket[start + tid] : -1;
  if (tid < 160) {
    int tt = tid / 20, d = tid - tt * 20;
    if (tt < tcnt) {
      int n = bucket[start + tt];
      sA[tt][d] = 0.5f * (aH[n * 20 + d] + aX[n * 20 + d]);
    } else {
      sA[tt][d] = 0.f;
    }
  }
  __syncthreads();
  if (tid < 8) {
    float nrm = 0.f;
    #pragma unroll
    for (int d = 0; d < 20; d++) nrm = fmaf(sA[tid][d], sA[tid][d], nrm);
    sN[tid] = nrm;
  }
  __syncthreads();

  // ---- distance tile: 8x20 @ 20x1024 ----
  const float* T = tab + (size_t)c * (21 * CAND_N);
  int j4 = tid * 4;
  float4 acc[8];
  #pragma unroll
  for (int tt = 0; tt < 8; tt++) acc[tt] = make_float4(0.f, 0.f, 0.f, 0.f);
  #pragma unroll
  for (int dq = 0; dq < 5; dq++) {
    float4 t0 = *(const float4*)(T + (dq * 4 + 0) * CAND_N + j4);
    float4 t1 = *(const float4*)(T + (dq * 4 + 1) * CAND_N + j4);
    float4 t2 = *(const float4*)(T + (dq * 4 + 2) * CAND_N + j4);
    float4 t3 = *(const float4*)(T + (dq * 4 + 3) * CAND_N + j4);
    #pragma unroll
    for (int tt = 0; tt < 8; tt++) {
      float4 av = *(const float4*)(&sA[tt][dq * 4]);   // LDS broadcast
      acc[tt].x = fmaf(av.x, t0.x, acc[tt].x);
      acc[tt].y = fmaf(av.x, t0.y, acc[tt].y);
      acc[tt].z = fmaf(av.x, t0.z, acc[tt].z);
      acc[tt].w = fmaf(av.x, t0.w, acc[tt].w);
      acc[tt].x = fmaf(av.y, t1.x, acc[tt].x);
      acc[tt].y = fmaf(av.y, t1.y, acc[tt].y);
      acc[tt].z = fmaf(av.y, t1.z, acc[tt].z);
      acc[tt].w = fmaf(av.y, t1.w, acc[tt].w);
      acc[tt].x = fmaf(av.z, t2.x, acc[tt].x);
      acc[tt].y = fmaf(av.z, t2.y, acc[tt].y);
      acc[tt].z = fmaf(av.z, t2.z, acc[tt].z);
      acc[tt].w = fmaf(av.z, t2.w, acc[tt].w);
      acc[tt].x = fmaf(av.w, t3.x, acc[tt].x);
      acc[tt].y = fmaf(av.w, t3.y, acc[tt].y);
      acc[tt].z = fmaf(av.w, t3.z, acc[tt].z);
      acc[tt].w = fmaf(av.w, t3.w, acc[tt].w);
    }
  }
  float4 cn4 = *(const float4*)(T + 20 * CAND_N + j4);
  #pragma unroll
  for (int tt = 0; tt < 8; tt++) {
    float4 d2;
    d2.x = sN[tt] + cn4.x - 2.f * acc[tt].x;
    d2.y = sN[tt] + cn4.y - 2.f * acc[tt].y;
    d2.z = sN[tt] + cn4.z - 2.f * acc[tt].z;
    d2.w = sN[tt] + cn4.w - 2.f * acc[tt].w;
    *(float4*)(&sD[tt][j4]) = d2;
  }
  __syncthreads();

  // ---- selection: wave w handles tokens w and w+4 ----
  int lane = tid & 63, w = tid >> 6;
  #pragma unroll 1
  for (int pass = 0; pass < 2; pass++) {
    int tt = w + 4 * pass;
    if (tt >= tcnt) continue;
    int n = sTok[tt];
    int xv = x[n];

    float v[16];
    #pragma unroll
    for (int m = 0; m < 16; m++) v[m] = sD[tt][m * 64 + lane];  // j = m*64+lane

    float acc0 = 0.f, acc1 = 0.f, esum = 0.f;
    #pragma unroll 1
    for (int r = 0; r < TOPK; r++) {
      float bv = v[0];
      int bj = lane;
      #pragma unroll
      for (int m = 1; m < 16; m++) {
        int jm = (m << 6) | lane;
        if (v[m] < bv) { bv = v[m]; bj = jm; }     // m asc => j asc, < keeps low j
      }
      #pragma unroll
      for (int o = 1; o < 64; o <<= 1) {
        float ov = __shfl_xor(bv, o);
        int   oj = __shfl_xor(bj, o);
        if (ov < bv || (ov == bv && oj < bj)) { bv = ov; bj = oj; }
      }
      float dist = sqrtf(fmaxf(bv, 1e-12f));
      float e = expf(expf(-RHO_C * dist));
      int id = cand[c * CAND_N + bj];
      esum += e;
      acc0 = fmaf(e, emb[(size_t)id * HID + lane], acc0);
      acc1 = fmaf(e, emb[(size_t)id * HID + 64 + lane], acc1);
      #pragma unroll
      for (int m = 0; m < 16; m++) {
        int jm = (m << 6) | lane;
        if (jm == bj) v[m] = 3.0e38f;
      }
    }
    const float e1 = 2.71828182845904523536f;      // exp(1.0) self slot
    esum += e1;
    acc0 = fmaf(e1, emb[(size_t)xv * HID + lane], acc0);
    acc1 = fmaf(e1, emb[(size_t)xv * HID + 64 + lane], acc1);
    float inv = 1.0f / esum;
    out[(size_t)n * HID + lane] = acc0 * inv;
    out[(size_t)n * HID + 64 + lane] = acc1 * inv;
  }
}

// ---------------------------------------------------------------------------
extern "C" void kernel_launch(void* const* d_in, const int* in_sizes, int n_in,
                              void* d_out, int out_size, void* d_ws, size_t ws_size,
                              hipStream_t stream) {
  const int*   x      = (const int*)d_in[0];
  const int*   t_slot = (const int*)d_in[1];
  const float* vecs   = (const float*)d_in[2];
  const float* embn   = (const float*)d_in[3];
  const int*   I_arr  = (const int*)d_in[4];
  const int*   cand   = (const int*)d_in[5];
  const float* temb   = (const float*)d_in[6];
  const float* Ws1    = (const float*)d_in[7];
  const float* bs1    = (const float*)d_in[8];
  const float* Ws2    = (const float*)d_in[9];
  const float* bs2    = (const float*)d_in[10];
  const float* Wto1   = (const float*)d_in[11];
  const float* bto1   = (const float*)d_in[12];
  const float* Wto2   = (const float*)d_in[13];
  const float* bto2   = (const float*)d_in[14];
  const float* Wti1   = (const float*)d_in[15];
  const float* bti1   = (const float*)d_in[16];
  const float* Wti2   = (const float*)d_in[17];
  const float* bti2   = (const float*)d_in[18];

  // workspace layout (~6.3 MB)
  float* tab    = (float*)d_ws;                       // 64*21*1024
  float* aX     = tab + NC * 21 * CAND_N;             // 5120*20
  float* aH     = aX + NTOK * 20;                     // 5120*20
  int*   bucket = (int*)(aH + NTOK * 20);             // 5120
  int*   blkInfo= bucket + NTOK;                      // 704
  float* outp   = (float*)d_out;

  k_pre<<<CAND_BLKS + TO_BLKS + SEQ_BLKS + 1, 256, 0, stream>>>(
      x, t_slot, vecs, temb, I_arr, cand,
      Ws1, bs1, Ws2, bs2, Wto1, bto1, Wto2, bto2,
      Wti1, bti1, Wti2, bti2,
      tab, aX, aH, bucket, blkInfo);
  k_distsel<<<MAXB, 256, 0, stream>>>(blkInfo, bucket, tab, aX, aH,
                                      x, cand, embn, outp);
}